// Round 9
// baseline (312.607 us; speedup 1.0000x reference)
//
#include <hip/hip_runtime.h>
#include <hip/hip_bf16.h>

#define B_      16
#define N_TOK   1024
#define DIM_    768
#define HEADS_  12
#define DHEAD   64
#define KRES_   9

#define QKV_E   (12582912)           // B*HEADS*N*DHEAD
#define ROWS_   (B_*HEADS_*N_TOK)    // 196608
#define ACH     4                    // attn n-chunks per (b,h)
#define PARTN   192                  // mean-partials per q/k (64 by * 3 bx)

typedef __attribute__((ext_vector_type(8))) short bf16x8;
typedef __attribute__((ext_vector_type(4))) short s16x4;
typedef __attribute__((ext_vector_type(4))) float f32x4;

__device__ inline short f2b(float f) {
  unsigned u = __builtin_bit_cast(unsigned, f);
  u += 0x7fff + ((u >> 16) & 1);   // round-to-nearest-even
  return (short)(u >> 16);
}
__device__ inline float b2f(short s) {
  unsigned u = ((unsigned)(unsigned short)s) << 16;
  return __builtin_bit_cast(float, u);
}

__device__ inline void gload16(const short* g, short* l) {
  __builtin_amdgcn_global_load_lds(
      (const __attribute__((address_space(1))) void*)g,
      (__attribute__((address_space(3))) void*)l, 16, 0, 0);
}

// ---------------------------------------------------------------------------
// x (f32) -> bf16, vectorized 8/thread
// ---------------------------------------------------------------------------
__global__ __launch_bounds__(256) void cvt_bf16_kernel(
    const float* __restrict__ in, short* __restrict__ out, int n8)
{
  int i = blockIdx.x * 256 + threadIdx.x;
  if (i >= n8) return;
  float4 a = ((const float4*)in)[2 * i];
  float4 b = ((const float4*)in)[2 * i + 1];
  bf16x8 v;
  v[0]=f2b(a.x); v[1]=f2b(a.y); v[2]=f2b(a.z); v[3]=f2b(a.w);
  v[4]=f2b(b.x); v[5]=f2b(b.y); v[6]=f2b(b.z); v[7]=f2b(b.w);
  ((bf16x8*)out)[i] = v;
}

// ---------------------------------------------------------------------------
// f32 [R][C] -> bf16 [C][R] (64x64 LDS tiles). R,C multiples of 64.
// ---------------------------------------------------------------------------
__global__ __launch_bounds__(256) void transpose_cvt_kernel(
    const float* __restrict__ in, short* __restrict__ out, int R, int C)
{
  __shared__ short t[64][65];
  int c0 = blockIdx.x * 64, r0 = blockIdx.y * 64;
#pragma unroll
  for (int p = 0; p < 4; ++p) {
    int r = (threadIdx.x >> 4) + p * 16;
    int c = (threadIdx.x & 15) * 4;
    float4 v = *(const float4*)(in + (size_t)(r0 + r) * C + c0 + c);
    t[c][r] = f2b(v.x); t[c + 1][r] = f2b(v.y);
    t[c + 2][r] = f2b(v.z); t[c + 3][r] = f2b(v.w);
  }
  __syncthreads();
#pragma unroll
  for (int p = 0; p < 4; ++p) {
    int oc = (threadIdx.x >> 4) + p * 16;
    int orr = (threadIdx.x & 15) * 4;
    s16x4 v = { t[oc][orr], t[oc][orr + 1], t[oc][orr + 2], t[oc][orr + 3] };
    *(s16x4*)(out + (size_t)(c0 + oc) * R + r0 + orr) = v;
  }
}

// ---------------------------------------------------------------------------
// 256x256-tile GEMM, 8 waves (2M x 4N), BK=32, double-buffered 64 KB LDS,
// counted vmcnt(4) (never 0 in steady state), raw s_barrier + sched_barrier
// fences, LDS XOR-swizzle (elem ^= ((row>>1)&3)<<3) applied both-sides:
// inverse-swizzled GLOBAL source for global_load_lds + swizzled frag reads
// (rule: linear LDS dest). setprio(1) around each MFMA cluster.
// Per wave: 128x64 output = 8 m-frags x 4 n-frags.
// MODE 0: fused q/k row-norm + mean partials, scatter bf16 -> [B,h,N,d].
// MODE 1: f32 + bias -> out.
// ---------------------------------------------------------------------------
template<int MODE>
__global__ __launch_bounds__(512, 2) void gemm256(
    const short* __restrict__ A, const short* __restrict__ BT,
    int N, int K, int nxblk,
    short* __restrict__ qkv_out, float* __restrict__ proj_out,
    const float* __restrict__ bias, float* __restrict__ partials)
{
  __shared__ short As[2][8192];   // 32 KB  (256 rows x 32 k, swizzled layout)
  __shared__ short Bs[2][8192];   // 32 KB

  const int tid  = threadIdx.x;
  const int lane = tid & 63;
  const int wid  = tid >> 6;      // 0..7
  const int wr   = wid >> 2;      // 0..1  (M)
  const int wc   = wid & 3;       // 0..3  (N)
  const int fr   = lane & 15;
  const int fq   = lane >> 4;     // 0..3

  // XCD swizzle (nwg % 8 == 0)
  const int nwg = (int)gridDim.x;
  const int cpx = nwg >> 3;
  const int swz = (blockIdx.x & 7) * cpx + (blockIdx.x >> 3);
  const int bx  = swz % nxblk, by = swz / nxblk;
  const int rowBase = by << 8;
  const int colBase = bx << 8;

  // staging invariants: thread covers row (tid>>2), k-group pre-swizzled
  const int srow = tid >> 2;                               // 0..127
  const int koff = ((tid & 3) * 8) ^ (((tid >> 3) & 3) << 3);
  const short* Asrc0 = A  + (size_t)(rowBase + srow) * K + koff;
  const short* Asrc1 = Asrc0 + (size_t)128 * K;
  const short* Bsrc0 = BT + (size_t)(colBase + srow) * K + koff;
  const short* Bsrc1 = Bsrc0 + (size_t)128 * K;

  // frag read offsets (shorts), swizzled
  int aoff[8], boff[4];
#pragma unroll
  for (int mf = 0; mf < 8; ++mf) {
    int r = wr * 128 + mf * 16 + fr;
    aoff[mf] = r * 32 + ((fq * 8) ^ (((r >> 1) & 3) << 3));
  }
#pragma unroll
  for (int nf = 0; nf < 4; ++nf) {
    int r = wc * 64 + nf * 16 + fr;
    boff[nf] = r * 32 + ((fq * 8) ^ (((r >> 1) & 3) << 3));
  }

  f32x4 acc[8][4];
#pragma unroll
  for (int i = 0; i < 8; ++i)
#pragma unroll
    for (int j = 0; j < 4; ++j) acc[i][j] = f32x4{0.f, 0.f, 0.f, 0.f};

  auto stage = [&](int bb, int k0) {
    gload16(Asrc0 + k0, &As[bb][tid * 8]);
    gload16(Asrc1 + k0, &As[bb][4096 + tid * 8]);
    gload16(Bsrc0 + k0, &Bs[bb][tid * 8]);
    gload16(Bsrc1 + k0, &Bs[bb][4096 + tid * 8]);
  };

  stage(0, 0);
  const int NT = K >> 5;
#pragma unroll 1
  for (int kt = 0; kt < NT; ++kt) {
    if (kt + 1 < NT) {
      stage((kt + 1) & 1, (kt + 1) << 5);      // prefetch stays in flight
      asm volatile("s_waitcnt vmcnt(4)" ::: "memory");   // current buf done
    } else {
      asm volatile("s_waitcnt vmcnt(0)" ::: "memory");
    }
    __builtin_amdgcn_sched_barrier(0);
    __builtin_amdgcn_s_barrier();
    __builtin_amdgcn_sched_barrier(0);

    const short* Ab = As[kt & 1];
    const short* Bb = Bs[kt & 1];
    bf16x8 bfr[4];
#pragma unroll
    for (int nf = 0; nf < 4; ++nf)
      bfr[nf] = *(const bf16x8*)(Bb + boff[nf]);
#pragma unroll
    for (int mp = 0; mp < 4; ++mp) {
      bf16x8 a0 = *(const bf16x8*)(Ab + aoff[2 * mp]);
      bf16x8 a1 = *(const bf16x8*)(Ab + aoff[2 * mp + 1]);
      __builtin_amdgcn_s_setprio(1);
#pragma unroll
      for (int nf = 0; nf < 4; ++nf) {
        acc[2 * mp][nf] =
            __builtin_amdgcn_mfma_f32_16x16x32_bf16(a0, bfr[nf], acc[2 * mp][nf], 0, 0, 0);
        acc[2 * mp + 1][nf] =
            __builtin_amdgcn_mfma_f32_16x16x32_bf16(a1, bfr[nf], acc[2 * mp + 1][nf], 0, 0, 0);
      }
      __builtin_amdgcn_s_setprio(0);
    }
    __builtin_amdgcn_sched_barrier(0);
    __builtin_amdgcn_s_barrier();
    __builtin_amdgcn_sched_barrier(0);
  }

  // ---- epilogue: D frag layout col = lane&15, row = fq*4 + e ----
  if (MODE == 0) {
    const int b    = rowBase >> 10;
    const int part = colBase / 768;                 // block-uniform
    const int hd   = ((colBase % 768) >> 6) + wc;   // one head per wave
    const size_t hbase = (size_t)part * QKV_E + ((size_t)(b * 12 + hd) << 16);
    float psum = 0.f;
#pragma unroll
    for (int mf = 0; mf < 8; ++mf) {
      if (part < 2) {
        float ss[4];
#pragma unroll
        for (int e = 0; e < 4; ++e) {
          float s = 0.f;
#pragma unroll
          for (int nf = 0; nf < 4; ++nf)
            s = fmaf(acc[mf][nf][e], acc[mf][nf][e], s);
          ss[e] = s;
        }
#pragma unroll
        for (int m = 1; m < 16; m <<= 1)
#pragma unroll
          for (int e = 0; e < 4; ++e) ss[e] += __shfl_xor(ss[e], m);
#pragma unroll
        for (int e = 0; e < 4; ++e) ss[e] = rsqrtf(ss[e]);
#pragma unroll
        for (int nf = 0; nf < 4; ++nf)
#pragma unroll
          for (int e = 0; e < 4; ++e) {
            acc[mf][nf][e] *= ss[e];
            psum += acc[mf][nf][e];
          }
      }
      const int nl = (rowBase & 1023) + wr * 128 + mf * 16 + fq * 4;
#pragma unroll
      for (int nf = 0; nf < 4; ++nf) {
        const int dd = nf * 16 + fr;
#pragma unroll
        for (int e = 0; e < 4; ++e)
          qkv_out[hbase + ((size_t)(nl + e) << 6) + dd] = f2b(acc[mf][nf][e]);
      }
    }
    if (part < 2) {
#pragma unroll
      for (int m = 1; m < 64; m <<= 1) psum += __shfl_xor(psum, m);
      float* sredf = (float*)As;      // LDS free after final barrier
      if (lane == 0) sredf[wid] = psum;
      __syncthreads();
      if (tid == 0) {
        float t = 0.f;
#pragma unroll
        for (int w = 0; w < 8; ++w) t += sredf[w];
        partials[part * PARTN + by * 3 + (bx - part * 3)] = t;
      }
    }
  } else {
    float bj[4];
#pragma unroll
    for (int nf = 0; nf < 4; ++nf) bj[nf] = bias[colBase + wc * 64 + nf * 16 + fr];
    const int gr0 = rowBase + wr * 128 + fq * 4;
#pragma unroll
    for (int mf = 0; mf < 8; ++mf)
#pragma unroll
      for (int nf = 0; nf < 4; ++nf) {
        const int gc = colBase + wc * 64 + nf * 16 + fr;
#pragma unroll
        for (int e = 0; e < 4; ++e)
          proj_out[(size_t)(gr0 + mf * 16 + e) * N + gc] = acc[mf][nf][e] + bj[nf];
      }
  }
}

__global__ __launch_bounds__(256) void mean_reduce_kernel(
    const float* __restrict__ partials, float* __restrict__ means)
{
  float sq = 0.f, sk = 0.f;
  for (int i = threadIdx.x; i < PARTN; i += 256) {
    sq += partials[i]; sk += partials[PARTN + i];
  }
#pragma unroll
  for (int o = 32; o; o >>= 1) { sq += __shfl_xor(sq, o); sk += __shfl_xor(sk, o); }
  __shared__ float s[8];
  int wid = threadIdx.x >> 6, lane = threadIdx.x & 63;
  if (lane == 0) { s[wid] = sq; s[4 + wid] = sk; }
  __syncthreads();
  if (threadIdx.x == 0) {
    means[0] = (s[0] + s[1] + s[2] + s[3]) / 12582912.f;
    means[1] = (s[4] + s[5] + s[6] + s[7]) / 12582912.f;
  }
}

// ---------------------------------------------------------------------------
// attn partials via ballot broadcast (unchanged from round 8)
// ---------------------------------------------------------------------------
__global__ __launch_bounds__(256) void attn_part_kernel(
    const short* __restrict__ k, const short* __restrict__ v,
    const float* __restrict__ means, float* __restrict__ part)
{
  __shared__ float red[64][64];
  int tid = threadIdx.x, lane = tid & 63, w = tid >> 6;
  int bh = blockIdx.x >> 2;
  int ch = blockIdx.x & 3;
  float mk = means[1];
  const short* kb = k + ((size_t)bh << 16) + (ch << 14);
  const short* vb = v + ((size_t)bh << 16) + (ch << 14);
  float acc[64];
#pragma unroll
  for (int dd = 0; dd < 64; ++dd) acc[dd] = 0.f;

  const int nbase = w << 6;
  for (int t = 0; t < 64; ++t) {
    int n = nbase + t;
    float kv = b2f(kb[(n << 6) + lane]);
    float vv = b2f(vb[(n << 6) + lane]);
    unsigned long long km = __ballot(kv > mk);
    unsigned lo = (unsigned)km, hi = (unsigned)(km >> 32);
#pragma unroll
    for (int dd = 0; dd < 32; ++dd) {
      float bitf = __builtin_bit_cast(float, ((lo >> dd) & 1u) ? 0x3f800000u : 0u);
      acc[dd] = fmaf(bitf, vv, acc[dd]);
    }
#pragma unroll
    for (int dd = 0; dd < 32; ++dd) {
      float bitf = __builtin_bit_cast(float, ((hi >> dd) & 1u) ? 0x3f800000u : 0u);
      acc[32 + dd] = fmaf(bitf, vv, acc[32 + dd]);
    }
  }

  for (int p = 0; p < 4; ++p) {
    if (w == p) {
#pragma unroll
      for (int dd = 0; dd < 64; ++dd) {
        if (p == 0) red[dd][lane] = acc[dd];
        else        red[dd][lane] += acc[dd];
      }
    }
    __syncthreads();
  }
  float* pp = part + ((size_t)blockIdx.x << 12);
  for (int idx = tid; idx < 4096; idx += 256)
    pp[idx] = red[idx >> 6][idx & 63];
}

__global__ __launch_bounds__(256) void attn_reduce_kernel(
    const float* __restrict__ part, float* __restrict__ attn)
{
  int idx = blockIdx.x * 256 + threadIdx.x;   // over 192*4096
  int bh  = idx >> 12;
  int off = idx & 4095;
  float s = 0.f;
#pragma unroll
  for (int c = 0; c < ACH; ++c)
    s += part[(((size_t)bh * ACH + c) << 12) + off];
  attn[idx] = s;
}

// ---------------------------------------------------------------------------
// out rows (unchanged from round 8)
// ---------------------------------------------------------------------------
__global__ __launch_bounds__(256) void out_kernel(
    const short* __restrict__ q, const short* __restrict__ v,
    const float* __restrict__ attn, const float* __restrict__ means,
    const float* __restrict__ wd, short* __restrict__ mid)
{
  __shared__ short v_s[136 * 64];     // rows n0-4 .. n0+131
  int tid = threadIdx.x, lane = tid & 63, wid = tid >> 6;
  int bh = blockIdx.x >> 3;
  int n0 = (blockIdx.x & 7) << 7;
  int h  = bh % 12;
  int b  = bh / 12;

  const short* vb = v + ((size_t)bh << 16);
  for (int i = tid; i < 2176; i += 256) {
    int r = i >> 4, c = (i & 15) << 2;
    int nn = n0 - 4 + r;
    s16x4 val = {0, 0, 0, 0};
    if (nn >= 0 && nn < N_TOK) val = *(const s16x4*)(vb + (nn << 6) + c);
    *(s16x4*)(v_s + (i << 2)) = val;
  }

  const float* ag = attn + ((size_t)bh << 12) + lane;
  float col[64];
#pragma unroll
  for (int dd = 0; dd < 64; ++dd) col[dd] = ag[dd << 6];

  float mq = means[0];
  float wc[9];
#pragma unroll
  for (int j = 0; j < 9; ++j) wc[j] = wd[h * 9 + j];
  __syncthreads();

  const short* qb = q + ((size_t)bh << 16);
  for (int t = 0; t < 32; ++t) {
    int ln = (wid << 5) + t;
    int n  = n0 + ln;
    float qv = b2f(qb[(n << 6) + lane]);
    unsigned long long qmask = __ballot((qv - mq) > 0.f);
    float acc = 0.f;
#pragma unroll
    for (int dd = 0; dd < 64; ++dd) {
      float bitf = (float)((unsigned)((qmask >> dd) & 1ull));
      acc = fmaf(bitf, col[dd], acc);
    }
    float vv = b2f(v_s[((ln + 4) << 6) + lane]);
    float o = 0.5f * vv + acc * 0.3183098861837907f;
    float ss = o * o;
#pragma unroll
    for (int off = 32; off; off >>= 1) ss += __shfl_xor(ss, off);
    o *= rsqrtf(ss);
#pragma unroll
    for (int j = 0; j < 9; ++j)
      o += wc[j] * b2f(v_s[((ln + j) << 6) + lane]);
    mid[(size_t)((b << 10) | n) * 768 + (h << 6) + lane] = f2b(o);
  }
}

extern "C" void kernel_launch(void* const* d_in, const int* in_sizes, int n_in,
                              void* d_out, int out_size, void* d_ws, size_t ws_size,
                              hipStream_t stream) {
  (void)in_sizes; (void)n_in; (void)out_size; (void)ws_size;
  const float* x       = (const float*)d_in[0];
  const float* w_qkv   = (const float*)d_in[3];
  const float* w_dconv = (const float*)d_in[4];
  const float* w_proj  = (const float*)d_in[5];
  const float* b_proj  = (const float*)d_in[6];

  // ---- workspace layout (phase-safe aliasing), ~130.5 MB ----
  char* ws = (char*)d_ws;
  short* qbuf = (short*)ws;                         // 3*QKV_E shorts
  short* kbuf = qbuf + QKV_E;
  short* vbuf = kbuf + QKV_E;
  char*  r2   = ws + (size_t)3 * QKV_E * 2;         // 3.54 MB region:
  short* wqkvT    = (short*)r2;                     //   phases 0-1 (3.54 MB)
  float* attn     = (float*)r2;                     //   phases 4-5 (3.15 MB)
  short* mid  = (short*)(r2 + 3538944);             // 25.2 MB, phases 5-6
  float* partials = (float*)mid;                    //   phases 1-2 (1.5 KB) —
                                                    //   mid unwritten till ph5
  char*  r4   = (char*)mid + (size_t)16384 * 768 * 2;
  short* xb        = (short*)r4;                    // 25.2 MB, phases 0-1
  float* attn_part = (float*)r4;                    //   reused ph 3 (12.6 MB)
  short* wprojT = (short*)(r4 + (size_t)QKV_E * 2); // 1.18 MB, phases 0,6
  float* means  = (float*)((char*)wprojT + (size_t)768 * 768 * 2);

  // 0) convert x -> bf16; transpose+convert weights
  cvt_bf16_kernel<<<QKV_E / 8 / 256, 256, 0, stream>>>(x, xb, QKV_E / 8);
  dim3 gt1(2304 / 64, 768 / 64);
  transpose_cvt_kernel<<<gt1, 256, 0, stream>>>(w_qkv, wqkvT, 768, 2304);
  dim3 gt2(768 / 64, 768 / 64);
  transpose_cvt_kernel<<<gt2, 256, 0, stream>>>(w_proj, wprojT, 768, 768);

  // 1) QKV GEMM (+fused q/k row-norm + mean partials) -> q,k,v [B,h,N,d]
  gemm256<0><<<(2304 / 256) * (16384 / 256), 512, 0, stream>>>(
      xb, wqkvT, 2304, 768, 9, qbuf, nullptr, nullptr, partials);

  // 2) global means of normalized q,k
  mean_reduce_kernel<<<1, 256, 0, stream>>>(partials, means);

  // 3-4) attn = binarized(k)^T v, ballot-broadcast partials + reduce
  attn_part_kernel<<<B_ * HEADS_ * ACH, 256, 0, stream>>>(kbuf, vbuf, means, attn_part);
  attn_reduce_kernel<<<B_ * HEADS_ * 4096 / 256, 256, 0, stream>>>(attn_part, attn);

  // 5) out rows -> mid bf16 [B,N,768]
  out_kernel<<<ROWS_ / 128, 256, 0, stream>>>(qbuf, vbuf, attn, means, w_dconv, mid);

  // 6) projection: mid @ wprojT^T + b_proj -> d_out f32
  gemm256<1><<<(768 / 256) * (16384 / 256), 512, 0, stream>>>(
      mid, wprojT, 768, 768, 3, nullptr, (float*)d_out, b_proj, nullptr);
}